// Round 1
// baseline (42.978 us; speedup 1.0000x reference)
//
#include <hip/hip_runtime.h>

#define W      1024
#define NROWS  16384          // 16 * 1 * 1024
#define NPIX   16777216.0     // 16 * 1024 * 1024
#define EPSF   1e-5f

// Kernel 1: one block per row. Box-filter window 9 along W (zero padded),
// per-pixel cc, block-level deterministic partial sum -> partials[row].
__global__ __launch_bounds__(256) void lncc_rows(const float* __restrict__ I,
                                                 const float* __restrict__ J,
                                                 float* __restrict__ partials) {
    __shared__ float sA[W + 8];   // [0..3] left halo zeros, [4..1027] row, [1028..1031] right halo zeros
    __shared__ float sB[W + 8];
    __shared__ float wsum[4];

    const int t   = threadIdx.x;
    const int row = blockIdx.x;
    const size_t base = (size_t)row * W;

    // Coalesced float4 loads: exactly one read of each input element.
    const float4 aown = *(const float4*)(I + base + 4 * t);
    const float4 bown = *(const float4*)(J + base + 4 * t);
    *(float4*)(&sA[4 + 4 * t]) = aown;
    *(float4*)(&sB[4 + 4 * t]) = bown;
    if (t < 4) {
        sA[t] = 0.f;        sB[t] = 0.f;
        sA[1028 + t] = 0.f; sB[1028 + t] = 0.f;
    }
    __syncthreads();

    // Window for this thread's 4 output pixels x0..x0+3 (x0 = 4t):
    // input x in [x0-4, x0+8) -> padded idx [4t, 4t+12).
    // middle 4 floats are this thread's own registers; read halo chunks from LDS.
    float a[12], b[12];
    {
        const float4 al = *(const float4*)(&sA[4 * t]);       // k = 0..3
        const float4 ar = *(const float4*)(&sA[4 * t + 8]);   // k = 8..11
        const float4 bl = *(const float4*)(&sB[4 * t]);
        const float4 br = *(const float4*)(&sB[4 * t + 8]);
        a[0]=al.x; a[1]=al.y; a[2]=al.z; a[3]=al.w;
        a[4]=aown.x; a[5]=aown.y; a[6]=aown.z; a[7]=aown.w;
        a[8]=ar.x; a[9]=ar.y; a[10]=ar.z; a[11]=ar.w;
        b[0]=bl.x; b[1]=bl.y; b[2]=bl.z; b[3]=bl.w;
        b[4]=bown.x; b[5]=bown.y; b[6]=bown.z; b[7]=bown.w;
        b[8]=br.x; b[9]=br.y; b[10]=br.z; b[11]=br.w;
    }

    // 5 sliding window sums, init over taps k=0..8 (first pixel).
    float sAc = 0.f, sBc = 0.f, sAA = 0.f, sBB = 0.f, sAB = 0.f;
#pragma unroll
    for (int k = 0; k < 9; ++k) {
        sAc += a[k];
        sBc += b[k];
        sAA = fmaf(a[k], a[k], sAA);
        sBB = fmaf(b[k], b[k], sBB);
        sAB = fmaf(a[k], b[k], sAB);
    }

    const float ninv = -(1.f / 9.f);
    float acc = 0.f;
#pragma unroll
    for (int p = 0; p < 4; ++p) {
        // cross = IJ_sum - I_sum*J_sum/9 ; var = X2_sum - X_sum^2/9  (exact algebra of reference)
        const float cross = fmaf(sAc * sBc, ninv, sAB);
        const float varA  = fmaf(sAc * sAc, ninv, sAA);
        const float varB  = fmaf(sBc * sBc, ninv, sBB);
        const float denom = fmaf(varA, varB, EPSF);
        acc += (cross * cross) * __builtin_amdgcn_rcpf(denom);
        if (p < 3) {
            const float an = a[9 + p], ao = a[p];
            const float bn = b[9 + p], bo = b[p];
            sAc += an - ao;
            sBc += bn - bo;
            sAA = fmaf(an, an, sAA); sAA = fmaf(ao, -ao, sAA);
            sBB = fmaf(bn, bn, sBB); sBB = fmaf(bo, -bo, sBB);
            sAB = fmaf(an, bn, sAB); sAB = fmaf(ao, -bo, sAB);
        }
    }

    // Deterministic block reduction: wave shuffle tree, then 4 wave partials.
#pragma unroll
    for (int off = 32; off > 0; off >>= 1)
        acc += __shfl_down(acc, off, 64);
    if ((t & 63) == 0) wsum[t >> 6] = acc;
    __syncthreads();
    if (t == 0) partials[row] = (wsum[0] + wsum[1]) + (wsum[2] + wsum[3]);
}

// Kernel 2: deterministic sum of 16384 partials (double accum), final transform.
__global__ __launch_bounds__(256) void lncc_finalize(const float* __restrict__ partials,
                                                     float* __restrict__ out) {
    __shared__ double sh[256];
    const int t = threadIdx.x;
    double s = 0.0;
    for (int i = t; i < NROWS; i += 256)
        s += (double)partials[i];
    sh[t] = s;
    __syncthreads();
    if (t == 0) {
        double tot = 0.0;
        for (int i = 0; i < 256; ++i) tot += sh[i];
        out[0] = (float)(1.0 - tot / NPIX);
    }
}

extern "C" void kernel_launch(void* const* d_in, const int* in_sizes, int n_in,
                              void* d_out, int out_size, void* d_ws, size_t ws_size,
                              hipStream_t stream) {
    const float* I = (const float*)d_in[0];
    const float* J = (const float*)d_in[1];
    float* partials = (float*)d_ws;          // 16384 floats = 64 KiB scratch
    float* out      = (float*)d_out;

    lncc_rows<<<NROWS, 256, 0, stream>>>(I, J, partials);
    lncc_finalize<<<1, 256, 0, stream>>>(partials, out);
}